// Round 1
// baseline (51.829 us; speedup 1.0000x reference)
//
#include <hip/hip_runtime.h>

#define B_N 8192
#define K_CL 64
#define INF_F 3.0e38f

// ws layout (floats): [0,8192) sortedX | [8192,16384) sortedY |
// [16384,16449) start offsets (int, 65) padded to 16512 | [16512,20608) hinges[64*64]

__global__ void sort_by_label_kernel(const int* __restrict__ labels,
                                     const float* __restrict__ coords,
                                     float* __restrict__ sx, float* __restrict__ sy,
                                     int* __restrict__ start) {
    __shared__ int hist[K_CL];
    __shared__ int offs[K_CL + 1];
    int tid = threadIdx.x;
    if (tid < K_CL) hist[tid] = 0;
    __syncthreads();
    for (int i = tid; i < B_N; i += blockDim.x)
        atomicAdd(&hist[labels[i]], 1);
    __syncthreads();
    if (tid == 0) {
        int run = 0;
        for (int k = 0; k < K_CL; ++k) { offs[k] = run; run += hist[k]; }
        offs[K_CL] = run;
    }
    __syncthreads();
    if (tid <= K_CL) start[tid] = offs[tid];
    if (tid < K_CL) hist[tid] = offs[tid];   // reuse as scatter cursor
    __syncthreads();
    for (int i = tid; i < B_N; i += blockDim.x) {
        int l = labels[i];
        int pos = atomicAdd(&hist[l], 1);
        float2 c = reinterpret_cast<const float2*>(coords)[i];
        sx[pos] = c.x;
        sy[pos] = c.y;
    }
}

__global__ void pair_min_kernel(const float* __restrict__ sx,
                                const float* __restrict__ sy,
                                const int* __restrict__ start,
                                float* __restrict__ hinges) {
    int ci = blockIdx.x, cj = blockIdx.y;
    if (ci >= cj) return;                 // uniform per block
    int iS = start[ci], nI = start[ci + 1] - iS;
    int jS = start[cj], nJ = start[cj + 1] - jS;
    int tid = threadIdx.x;
    __shared__ float jx[256], jy[256];
    float myMin = INF_F;
    for (int i0 = 0; i0 < nI; i0 += 256) {
        bool valid = (i0 + tid) < nI;
        float xi = 0.0f, yi = 0.0f;
        if (valid) { xi = sx[iS + i0 + tid]; yi = sy[iS + i0 + tid]; }
        for (int j0 = 0; j0 < nJ; j0 += 256) {
            __syncthreads();
            if (j0 + tid < nJ) { jx[tid] = sx[jS + j0 + tid]; jy[tid] = sy[jS + j0 + tid]; }
            __syncthreads();
            if (valid) {
                int cnt = min(256, nJ - j0);
                for (int k = 0; k < cnt; ++k) {
                    float dx = xi - jx[k];
                    float dy = yi - jy[k];
                    float d2 = dx * dx + dy * dy;
                    myMin = fminf(myMin, d2);
                }
            }
        }
    }
    // block-reduce min: wave64 shuffle then LDS across 4 waves
    for (int off = 32; off > 0; off >>= 1)
        myMin = fminf(myMin, __shfl_down(myMin, off, 64));
    __shared__ float wmin[4];
    int wave = tid >> 6, lane = tid & 63;
    if (lane == 0) wmin[wave] = myMin;
    __syncthreads();
    if (tid == 0) {
        float m = fminf(fminf(wmin[0], wmin[1]), fminf(wmin[2], wmin[3]));
        float h = 1.0f - sqrtf(m);
        hinges[ci * K_CL + cj] = h > 0.0f ? h : 0.0f;
    }
}

__global__ void reduce_hinge_kernel(const float* __restrict__ hinges,
                                    float* __restrict__ out) {
    int tid = threadIdx.x;
    float s = 0.0f;
    for (int p = tid; p < K_CL * K_CL; p += 256) {
        int ci = p >> 6, cj = p & 63;
        if (ci < cj) s += hinges[p];
    }
    for (int off = 32; off > 0; off >>= 1)
        s += __shfl_down(s, off, 64);
    __shared__ float wsum[4];
    int wave = tid >> 6, lane = tid & 63;
    if (lane == 0) wsum[wave] = s;
    __syncthreads();
    if (tid == 0)
        out[0] = (wsum[0] + wsum[1] + wsum[2] + wsum[3]) / 2016.0f;
}

extern "C" void kernel_launch(void* const* d_in, const int* in_sizes, int n_in,
                              void* d_out, int out_size, void* d_ws, size_t ws_size,
                              hipStream_t stream) {
    const int*   labels = (const int*)d_in[1];     // cluster_labels (int32)
    const float* coords = (const float*)d_in[2];   // manifold_coords [8192,2] f32
    float* out = (float*)d_out;

    float* sx     = (float*)d_ws;
    float* sy     = sx + B_N;
    int*   start  = (int*)(sy + B_N);
    float* hinges = (float*)d_ws + 2 * B_N + 128;  // aligned past 65 ints

    sort_by_label_kernel<<<1, 256, 0, stream>>>(labels, coords, sx, sy, start);
    dim3 grid(K_CL, K_CL);
    pair_min_kernel<<<grid, 256, 0, stream>>>(sx, sy, start, hinges);
    reduce_hinge_kernel<<<1, 256, 0, stream>>>(hinges, out);
}